// Round 6
// baseline (158.364 us; speedup 1.0000x reference)
//
#include <hip/hip_runtime.h>

// N=100000 nodes, E=1600000 edges, D=64.
// Pipeline: zero(ovfcnt) -> bin3_conv (single-pass cell binning, no hist,
//           1024-thr tiles + bf16 conv) -> aggregate6 (per-64-row bucket:
//           LDS counting sort + round0-style per-wave-row register gather).
//
// Cells: slab[b][tile][16] = one 64B line, written only by block `tile`
// (no cross-block line sharing). cnts[tile][b] = raw per-cell count
// (= final LDS cursor; no histogram pass needed).
#define D_FEAT 64
#define RB 64                 // rows per bucket -> nb = ceil(N/64) = 1563
#define RBITS 6
#define CELLCAP 16            // slots per (bucket,tile) cell = 64 B line
#define E_BLK 8192            // edges per binning tile -> ebt = 196
#define TMAX 256              // max tiles (E <= 2.09M)
#define NBMAX2 1600           // max buckets
#define SCAP 2048             // scol capacity (bucket mean 1024, sd 32)
#define OVCAP 65536           // overflow side list (expected ~10 used)

__device__ inline unsigned short f2bf(float f) {
    unsigned u = __float_as_uint(f);
    u += 0x7FFFu + ((u >> 16) & 1u);   // RNE
    return (unsigned short)(u >> 16);
}
__device__ inline float bf_lo(unsigned u) { return __uint_as_float(u << 16); }
__device__ inline float bf_hi(unsigned u) { return __uint_as_float(u & 0xFFFF0000u); }

// ---------------- K0: zero the overflow counter ----------------------------
__global__ __launch_bounds__(64)
void zero_kernel(int* __restrict__ p, int n) {
    int i = blockIdx.x * 64 + threadIdx.x;
    if (i < n) p[i] = 0;
}

// ---------------- K1: single-pass cell binning (+ bf16 conv) ---------------
__global__ __launch_bounds__(1024)
void bin3_conv_kernel(const int* __restrict__ row, const int* __restrict__ col,
                      int* __restrict__ cnts,       // [ebt][nb] raw cell counts
                      int* __restrict__ slab,       // [nb][ebt][CELLCAP]
                      int* __restrict__ ovfcnt,     // 1 int, pre-zeroed
                      int2* __restrict__ ovf,       // [OVCAP]
                      int n_edges, int ebt, int nb,
                      const float* __restrict__ feat, unsigned short* __restrict__ feat_bf,
                      int n4) {
    int gb = blockIdx.x;
    int t = threadIdx.x;
    if (gb < ebt) {
        __shared__ int cur[NBMAX2];
        for (int i = t; i < nb; i += 1024) cur[i] = 0;
        __syncthreads();
        int e0 = gb * E_BLK, e1 = min(e0 + E_BLK, n_edges);
        for (int e = e0 + t; e < e1; e += 1024) {
            int r = row[e], c = col[e];
            int b = r >> RBITS;
            int pos = atomicAdd(&cur[b], 1);              // LDS atomic only
            if (pos < CELLCAP) {
                slab[((size_t)b * ebt + gb) * CELLCAP + pos] = ((r & (RB - 1)) << 17) | c;
            } else {
                int op = atomicAdd(ovfcnt, 1);            // ~10 total
                if (op < OVCAP) ovf[op] = make_int2(r, c);
            }
        }
        __syncthreads();
        for (int i = t; i < nb; i += 1024)
            cnts[(size_t)gb * nb + i] = cur[i];           // coalesced row write
    } else {
        int i = (gb - ebt) * 1024 + t;
        if (i < n4) {
            float4 f = reinterpret_cast<const float4*>(feat)[i];
            ushort4 u;
            u.x = f2bf(f.x); u.y = f2bf(f.y); u.z = f2bf(f.z); u.w = f2bf(f.w);
            reinterpret_cast<ushort4*>(feat_bf)[i] = u;
        }
    }
}

// ---------------- K2: per-bucket sort + per-wave-row register gather -------
// Block b (512 thr, 8 waves): counting-sorts its contiguous 12.5 KB cell
// strip into scol (local CSR), then wave w gathers rows {w, w+8, ..., w+56}
// with round0's mapping: q=lane>>3 edge-slot, sub=lane&7 feature-slot ->
// 2 x 1KB wave-gathers per row (16 edges in flight), shfl fold, direct write.
template<int BF>
__global__ __launch_bounds__(512, 4)
void aggregate6_kernel(const float* __restrict__ feat,
                       const unsigned short* __restrict__ feat_bf,
                       const int* __restrict__ slab,
                       const int* __restrict__ cnts,
                       const int* __restrict__ ovfcnt,
                       const int2* __restrict__ ovf,
                       const int* __restrict__ row, const int* __restrict__ col,
                       float* __restrict__ out, int n_nodes, int n_edges,
                       int nb, int ebt) {
    __shared__ int cellc[TMAX];               // 1 KB
    __shared__ int scol[SCAP];                // 8 KB
    __shared__ int cnt[RB], csum[RB], cur[RB], ddeg[RB];
    __shared__ int sred[512];                 // 2 KB

    int b = blockIdx.x;
    int t = threadIdx.x;
    int w = t >> 6, lane = t & 63;
    int q = lane >> 3, sub = lane & 7;

    for (int i = t; i < ebt; i += 512) cellc[i] = cnts[(size_t)i * nb + b];
    if (t < RB) { cnt[t] = 0; ddeg[t] = 0; }
    __syncthreads();

    int pt = 0;
    for (int i = t; i < ebt; i += 512) pt += cellc[i];
    sred[t] = pt;
    __syncthreads();
    for (int o = 256; o > 0; o >>= 1) {
        if (t < o) sred[t] += sred[t + o];
        __syncthreads();
    }
    int btotal = sred[0];                     // raw edges for bucket b
    int rawoc = *ovfcnt;
    int oc = min(rawoc, OVCAP);
    bool fb = (btotal > SCAP) || (rawoc > OVCAP);

#define GATHER(cv, A)                                                          \
    do {                                                                       \
        if (BF) {                                                              \
            uint4 d = *reinterpret_cast<const uint4*>(                         \
                feat_bf + (size_t)(cv)*D_FEAT + sub * 8);                      \
            A[0] += bf_lo(d.x); A[1] += bf_hi(d.x);                            \
            A[2] += bf_lo(d.y); A[3] += bf_hi(d.y);                            \
            A[4] += bf_lo(d.z); A[5] += bf_hi(d.z);                            \
            A[6] += bf_lo(d.w); A[7] += bf_hi(d.w);                            \
        } else {                                                               \
            float4 x0 = *reinterpret_cast<const float4*>(                      \
                feat + (size_t)(cv)*D_FEAT + sub * 8);                         \
            float4 x1 = *reinterpret_cast<const float4*>(                      \
                feat + (size_t)(cv)*D_FEAT + sub * 8 + 4);                     \
            A[0] += x0.x; A[1] += x0.y; A[2] += x0.z; A[3] += x0.w;            \
            A[4] += x1.x; A[5] += x1.y; A[6] += x1.z; A[7] += x1.w;            \
        }                                                                      \
    } while (0)

    if (!fb) {
        int nslots = ebt * CELLCAP;           // 3136
        const int* sp = slab + (size_t)b * nslots;
        // pass 1: count rows (valid slots + overflow entries)
        for (int i = t; i < nslots; i += 512) {
            int cell = i >> 4, pos = i & 15;
            if (pos < min(cellc[cell], CELLCAP))
                atomicAdd(&cnt[((unsigned)sp[i]) >> 17], 1);
        }
        for (int i = t; i < oc; i += 512) {
            int2 rc = ovf[i];
            if ((rc.x >> RBITS) == b) atomicAdd(&cnt[rc.x & (RB - 1)], 1);
        }
        __syncthreads();
        if (t < RB) csum[t] = cnt[t];
        __syncthreads();
        for (int o = 1; o < RB; o <<= 1) {
            int v = (t < RB && t >= o) ? csum[t - o] : 0;
            __syncthreads();
            if (t < RB) csum[t] += v;
            __syncthreads();
        }
        if (t < RB) cur[t] = csum[t] - cnt[t];
        __syncthreads();
        // pass 2: scatter cols row-grouped into scol (btotal <= SCAP)
        for (int i = t; i < nslots; i += 512) {
            int cell = i >> 4, pos = i & 15;
            if (pos < min(cellc[cell], CELLCAP)) {
                int pk = sp[i];
                scol[atomicAdd(&cur[((unsigned)pk) >> 17], 1)] = pk & 0x1FFFF;
            }
        }
        for (int i = t; i < oc; i += 512) {
            int2 rc = ovf[i];
            if ((rc.x >> RBITS) == b)
                scol[atomicAdd(&cur[rc.x & (RB - 1)], 1)] = rc.y;
        }
        __syncthreads();
        // gather: wave w owns rows w, w+8, ..., w+56
        #pragma unroll 2
        for (int rr = 0; rr < 8; ++rr) {
            int lr = w + rr * 8;
            int r = b * RB + lr;
            if (r >= n_nodes) continue;
            int deg = cnt[lr];
            int s0 = csum[lr] - deg;
            float a0[8], a1[8];
            #pragma unroll
            for (int k = 0; k < 8; ++k) { a0[k] = 0.f; a1[k] = 0.f; }
            for (int base = 0; base < deg; base += 16) {
                int j0 = base + q, j1 = base + 8 + q;
                int c0 = (j0 < deg) ? scol[s0 + j0] : -1;
                int c1 = (j1 < deg) ? scol[s0 + j1] : -1;
                if (c0 >= 0) GATHER(c0, a0);
                if (c1 >= 0) GATHER(c1, a1);
            }
            #pragma unroll
            for (int k = 0; k < 8; ++k) a0[k] += a1[k];
            #pragma unroll
            for (int k = 0; k < 8; ++k) {
                a0[k] += __shfl_xor(a0[k], 8, 64);
                a0[k] += __shfl_xor(a0[k], 16, 64);
                a0[k] += __shfl_xor(a0[k], 32, 64);
            }
            if (q == 0) {
                float inv = 1.0f / fmaxf((float)deg, 1.0f);
                size_t off = (size_t)r * D_FEAT + sub * 8;
                float4 f0 = *reinterpret_cast<const float4*>(feat + off);
                float4 f1 = *reinterpret_cast<const float4*>(feat + off + 4);
                float4 o0, o1;
                o0.x = f0.x + a0[0] * inv; o0.y = f0.y + a0[1] * inv;
                o0.z = f0.z + a0[2] * inv; o0.w = f0.w + a0[3] * inv;
                o1.x = f1.x + a0[4] * inv; o1.y = f1.y + a0[5] * inv;
                o1.z = f1.z + a0[6] * inv; o1.w = f1.w + a0[7] * inv;
                *reinterpret_cast<float4*>(out + off) = o0;
                *reinterpret_cast<float4*>(out + off + 4) = o1;
            }
        }
    } else {
        // correctness-only fallback: chunked rescan; out used as scratch sum
        for (int j = t; j < RB * 16; j += 512) {
            int lr = j >> 4, r = b * RB + lr;
            if (r < n_nodes) {
                float4 z = make_float4(0.f, 0.f, 0.f, 0.f);
                *reinterpret_cast<float4*>(out + (size_t)r * D_FEAT + (j & 15) * 4) = z;
            }
        }
        __syncthreads();
        for (int base0 = 0; base0 < n_edges; base0 += SCAP) {
            int ce = min(SCAP, n_edges - base0);
            if (t < RB) cnt[t] = 0;
            __syncthreads();
            for (int i = t; i < ce; i += 512) {
                int r = row[base0 + i];
                if ((r >> RBITS) == b) atomicAdd(&cnt[r & (RB - 1)], 1);
            }
            __syncthreads();
            if (t < RB) csum[t] = cnt[t];
            __syncthreads();
            for (int o = 1; o < RB; o <<= 1) {
                int v = (t < RB && t >= o) ? csum[t - o] : 0;
                __syncthreads();
                if (t < RB) csum[t] += v;
                __syncthreads();
            }
            if (t < RB) { cur[t] = csum[t] - cnt[t]; ddeg[t] += cnt[t]; }
            __syncthreads();
            for (int i = t; i < ce; i += 512) {
                int r = row[base0 + i];
                if ((r >> RBITS) == b)
                    scol[atomicAdd(&cur[r & (RB - 1)], 1)] = col[base0 + i];
            }
            __syncthreads();
            for (int rr = 0; rr < 8; ++rr) {
                int lr = w + rr * 8;
                int r = b * RB + lr;
                if (r >= n_nodes) continue;
                int deg = cnt[lr];
                int s0 = csum[lr] - deg;
                float a0[8], a1[8];
                #pragma unroll
                for (int k = 0; k < 8; ++k) { a0[k] = 0.f; a1[k] = 0.f; }
                for (int base = 0; base < deg; base += 16) {
                    int j0 = base + q, j1 = base + 8 + q;
                    int c0 = (j0 < deg) ? scol[s0 + j0] : -1;
                    int c1 = (j1 < deg) ? scol[s0 + j1] : -1;
                    if (c0 >= 0) GATHER(c0, a0);
                    if (c1 >= 0) GATHER(c1, a1);
                }
                #pragma unroll
                for (int k = 0; k < 8; ++k) a0[k] += a1[k];
                #pragma unroll
                for (int k = 0; k < 8; ++k) {
                    a0[k] += __shfl_xor(a0[k], 8, 64);
                    a0[k] += __shfl_xor(a0[k], 16, 64);
                    a0[k] += __shfl_xor(a0[k], 32, 64);
                }
                if (q == 0) {
                    size_t off = (size_t)r * D_FEAT + sub * 8;
                    float4 s0v = *reinterpret_cast<const float4*>(out + off);
                    float4 s1v = *reinterpret_cast<const float4*>(out + off + 4);
                    s0v.x += a0[0]; s0v.y += a0[1]; s0v.z += a0[2]; s0v.w += a0[3];
                    s1v.x += a0[4]; s1v.y += a0[5]; s1v.z += a0[6]; s1v.w += a0[7];
                    *reinterpret_cast<float4*>(out + off) = s0v;
                    *reinterpret_cast<float4*>(out + off + 4) = s1v;
                }
            }
            __syncthreads();
        }
        // final: out = feat + out/deg
        for (int j = t; j < RB * 16; j += 512) {
            int lr = j >> 4, r = b * RB + lr;
            if (r < n_nodes) {
                int f = (j & 15) * 4;
                float inv = 1.0f / fmaxf((float)ddeg[lr], 1.0f);
                size_t off = (size_t)r * D_FEAT + f;
                float4 s = *reinterpret_cast<const float4*>(out + off);
                float4 fv = *reinterpret_cast<const float4*>(feat + off);
                float4 o;
                o.x = fv.x + s.x * inv; o.y = fv.y + s.y * inv;
                o.z = fv.z + s.z * inv; o.w = fv.w + s.w * inv;
                *reinterpret_cast<float4*>(out + off) = o;
            }
        }
    }
#undef GATHER
}

extern "C" void kernel_launch(void* const* d_in, const int* in_sizes, int n_in,
                              void* d_out, int out_size, void* d_ws, size_t ws_size,
                              hipStream_t stream) {
    const float* feat = (const float*)d_in[0];
    const int* row = (const int*)d_in[1];
    const int* col = (const int*)d_in[2];
    float* out = (float*)d_out;

    const int n_nodes = in_sizes[0] / D_FEAT;
    const int n_edges = in_sizes[1];
    const int nb = (n_nodes + RB - 1) / RB;               // 1563
    const int ebt = (n_edges + E_BLK - 1) / E_BLK;        // 196  (<= TMAX)
    const int n4 = n_nodes * D_FEAT / 4;                  // 1.6M float4s

    size_t slab_bytes = (size_t)nb * ebt * CELLCAP * 4;   // 19.6 MB
    size_t cnts_bytes = (size_t)ebt * nb * 4;             // 1.2 MB
    size_t ovf_bytes  = (size_t)OVCAP * 8;                // 0.5 MB
    size_t bf_bytes   = (size_t)n_nodes * D_FEAT * 2;     // 12.8 MB

    size_t lean_need = slab_bytes + cnts_bytes + ovf_bytes + 512;
    size_t fat_need  = lean_need + ((bf_bytes + 63) & ~(size_t)63);
    bool fat = (ws_size >= fat_need);

    char* ws = (char*)d_ws;
    size_t p = 0;
    int* slab = (int*)(ws + p); p += slab_bytes;          // 64B-aligned cells
    int* cnts = (int*)(ws + p); p += cnts_bytes;
    int2* ovf = (int2*)(ws + p); p += ovf_bytes;
    int* ovfcnt = (int*)(ws + p); p += 64;
    p = (p + 63) & ~(size_t)63;
    unsigned short* feat_bf = nullptr;
    if (fat) { feat_bf = (unsigned short*)(ws + p); }

    zero_kernel<<<1, 64, 0, stream>>>(ovfcnt, 1);

    {
        int conv_blocks = fat ? (n4 + 1023) / 1024 : 0;
        bin3_conv_kernel<<<ebt + conv_blocks, 1024, 0, stream>>>(
            row, col, cnts, slab, ovfcnt, ovf, n_edges, ebt, nb,
            feat, feat_bf, fat ? n4 : 0);
    }
    if (fat) {
        aggregate6_kernel<1><<<nb, 512, 0, stream>>>(
            feat, feat_bf, slab, cnts, ovfcnt, ovf, row, col,
            out, n_nodes, n_edges, nb, ebt);
    } else {
        aggregate6_kernel<0><<<nb, 512, 0, stream>>>(
            feat, nullptr, slab, cnts, ovfcnt, ovf, row, col,
            out, n_nodes, n_edges, nb, ebt);
    }
}

// Round 7
// 134.724 us; speedup vs baseline: 1.1755x; 1.1755x over previous
//
#include <hip/hip_runtime.h>

// N=100000 nodes, E=1600000 edges, D=64.
// Pipeline (2 launches, exact for any input, no overflow paths):
//  K1 bin5_conv: per 8192-edge tile, LDS counting sort by 256-row coarse
//     bucket -> write tile's edges as ONE compact coalesced 32KB block
//     (tilebuf) + per-tile bucket offsets (csumG). Also bf16-converts feat.
//  K2 agg7: block = coarse bucket (1024 thr, 16 waves, 256 rows). Reads its
//     per-tile runs, LDS counting-sorts into scol, then 8-lane groups own
//     2 rows each (16 gather chains in flight per wave), direct write.
#define D_FEAT 64
#define CB 256                // rows per coarse bucket -> nb2 = 391
#define CBITS 8
#define NB2MAX 512            // >= nb2+1
#define E_BLK 8192            // edges per tile -> ebt = 196
#define TMAX 256              // max tiles (E <= 2.09M)
#define SCAP 4608             // scol chunk capacity (bucket mean 4096, sd 64)

__device__ inline unsigned short f2bf(float f) {
    unsigned u = __float_as_uint(f);
    u += 0x7FFFu + ((u >> 16) & 1u);   // RNE
    return (unsigned short)(u >> 16);
}
__device__ inline float bf_lo(unsigned u) { return __uint_as_float(u << 16); }
__device__ inline float bf_hi(unsigned u) { return __uint_as_float(u & 0xFFFF0000u); }

// ---------------- K1: LDS counting sort per tile -> compact coalesced out --
__global__ __launch_bounds__(1024, 4)
void bin5_conv_kernel(const int* __restrict__ row, const int* __restrict__ col,
                      int* __restrict__ tilebuf,   // [ebt][E_BLK] compact sorted
                      int* __restrict__ csumG,     // [ebt][nb2+1] excl offsets
                      int n_edges, int ebt, int nb2,
                      const float* __restrict__ feat,
                      unsigned short* __restrict__ feat_bf, int n4) {
    int gb = blockIdx.x;
    int t = threadIdx.x;
    if (gb < ebt) {
        __shared__ int hist[NB2MAX];   // counts -> exclusive starts -> cursors
        __shared__ int scn[NB2MAX];
        __shared__ int ebuf[E_BLK];    // 32 KB sorted (pk = lr<<17 | col)
        for (int i = t; i < nb2; i += 1024) hist[i] = 0;
        __syncthreads();
        int e0 = gb * E_BLK, e1 = min(e0 + E_BLK, n_edges);
        int ne = e1 - e0;
        int rr[8], cc[8];
        #pragma unroll
        for (int k = 0; k < 8; ++k) {
            int i = t + k * 1024;
            if (i < ne) { rr[k] = row[e0 + i]; cc[k] = col[e0 + i]; }
            else rr[k] = -1;
        }
        #pragma unroll
        for (int k = 0; k < 8; ++k)
            if (rr[k] >= 0) atomicAdd(&hist[rr[k] >> CBITS], 1);
        __syncthreads();
        // inclusive scan hist -> scn
        if (t < nb2) scn[t] = hist[t];
        __syncthreads();
        for (int o = 1; o < nb2; o <<= 1) {
            int v = (t < nb2 && t >= o) ? scn[t - o] : 0;
            __syncthreads();
            if (t < nb2) scn[t] += v;
            __syncthreads();
        }
        // hist := exclusive start (also the scatter cursor)
        if (t < nb2) hist[t] = scn[t] - hist[t];
        __syncthreads();
        // write per-tile offsets (+ sentinel = ne)
        for (int i = t; i < nb2 + 1; i += 1024)
            csumG[(size_t)gb * (nb2 + 1) + i] = (i < nb2) ? hist[i] : ne;
        __syncthreads();   // csumG reads hist before scatter mutates it
        #pragma unroll
        for (int k = 0; k < 8; ++k) {
            if (rr[k] >= 0) {
                int b = rr[k] >> CBITS;
                int pos = atomicAdd(&hist[b], 1);
                ebuf[pos] = ((rr[k] & (CB - 1)) << 17) | cc[k];  // col < 2^17
            }
        }
        __syncthreads();
        for (int i = t; i < ne; i += 1024)                    // coalesced
            tilebuf[(size_t)gb * E_BLK + i] = ebuf[i];
    } else {
        int i = (gb - ebt) * 1024 + t;
        if (i < n4) {
            float4 f = reinterpret_cast<const float4*>(feat)[i];
            ushort4 u;
            u.x = f2bf(f.x); u.y = f2bf(f.y); u.z = f2bf(f.z); u.w = f2bf(f.w);
            reinterpret_cast<ushort4*>(feat_bf)[i] = u;
        }
    }
}

// ---------------- K2: per-coarse-bucket sort + 2-rows-per-group gather -----
template<int BF>
__global__ __launch_bounds__(1024, 8)
void agg7_kernel(const float* __restrict__ feat,
                 const unsigned short* __restrict__ feat_bf,
                 const int* __restrict__ tilebuf,
                 const int* __restrict__ csumG,
                 float* __restrict__ out, int n_nodes, int ebt, int nb2) {
    __shared__ int tstart[TMAX], tlen[TMAX], psum[TMAX];   // 3 KB
    __shared__ int scol[SCAP];                             // 18.4 KB
    __shared__ int cnt[CB], csum[CB], cur[CB], ddeg[CB];   // 4 KB

    int cb = blockIdx.x;
    int t = threadIdx.x;
    int w = t >> 6, lane = t & 63;
    int q = lane >> 3, sub = lane & 7;
    int rA = w * 16 + q;          // this group's two rows
    int rB = rA + 8;

    for (int i = t; i < ebt; i += 1024) {
        int s = csumG[(size_t)i * (nb2 + 1) + cb];
        int e = csumG[(size_t)i * (nb2 + 1) + cb + 1];
        tstart[i] = s; tlen[i] = e - s;
    }
    if (t < CB) ddeg[t] = 0;
    __syncthreads();
    if (t < ebt) psum[t] = tlen[t];
    __syncthreads();
    for (int o = 1; o < ebt; o <<= 1) {
        int v = (t < ebt && t >= o) ? psum[t - o] : 0;
        __syncthreads();
        if (t < ebt) psum[t] += v;
        __syncthreads();
    }
    int total = psum[ebt - 1];

    float acc[16];
    #pragma unroll
    for (int k = 0; k < 16; ++k) acc[k] = 0.f;

#define GATHER(cv, o0)                                                         \
    do {                                                                       \
        if (BF) {                                                              \
            uint4 d = *reinterpret_cast<const uint4*>(                         \
                feat_bf + (size_t)(cv)*D_FEAT + sub * 8);                      \
            acc[o0+0] += bf_lo(d.x); acc[o0+1] += bf_hi(d.x);                  \
            acc[o0+2] += bf_lo(d.y); acc[o0+3] += bf_hi(d.y);                  \
            acc[o0+4] += bf_lo(d.z); acc[o0+5] += bf_hi(d.z);                  \
            acc[o0+6] += bf_lo(d.w); acc[o0+7] += bf_hi(d.w);                  \
        } else {                                                               \
            float4 x0 = *reinterpret_cast<const float4*>(                      \
                feat + (size_t)(cv)*D_FEAT + sub * 8);                         \
            float4 x1 = *reinterpret_cast<const float4*>(                      \
                feat + (size_t)(cv)*D_FEAT + sub * 8 + 4);                     \
            acc[o0+0] += x0.x; acc[o0+1] += x0.y;                              \
            acc[o0+2] += x0.z; acc[o0+3] += x0.w;                              \
            acc[o0+4] += x1.x; acc[o0+5] += x1.y;                              \
            acc[o0+6] += x1.z; acc[o0+7] += x1.w;                              \
        }                                                                      \
    } while (0)

    // chunk loop over the flat concatenated edge stream (1 pass normally)
    for (int L = 0; L < total; L += SCAP) {
        int R = min(L + SCAP, total);
        if (t < CB) cnt[t] = 0;
        __syncthreads();
        // count: wave w walks tiles w, w+16, ...
        for (int tt = w; tt < ebt; tt += 16) {
            int pre = psum[tt] - tlen[tt];
            int lo = max(L - pre, 0), hi = min(tlen[tt], R - pre);
            const int* tp = tilebuf + (size_t)tt * E_BLK + tstart[tt];
            for (int i = lo + lane; i < hi; i += 64)
                atomicAdd(&cnt[((unsigned)tp[i]) >> 17], 1);
        }
        __syncthreads();
        if (t < CB) csum[t] = cnt[t];
        __syncthreads();
        for (int o = 1; o < CB; o <<= 1) {
            int v = (t < CB && t >= o) ? csum[t - o] : 0;
            __syncthreads();
            if (t < CB) csum[t] += v;
            __syncthreads();
        }
        if (t < CB) { cur[t] = csum[t] - cnt[t]; ddeg[t] += cnt[t]; }
        __syncthreads();
        // scatter row-grouped into scol
        for (int tt = w; tt < ebt; tt += 16) {
            int pre = psum[tt] - tlen[tt];
            int lo = max(L - pre, 0), hi = min(tlen[tt], R - pre);
            const int* tp = tilebuf + (size_t)tt * E_BLK + tstart[tt];
            for (int i = lo + lane; i < hi; i += 64) {
                int pk = tp[i];
                scol[atomicAdd(&cur[((unsigned)pk) >> 17], 1)] = pk & 0x1FFFF;
            }
        }
        __syncthreads();
        // gather: 2 rows per 8-lane group, 2 chains in flight, unrolled 2
        int cA = cnt[rA], sA = csum[rA] - cA;
        int cB2 = cnt[rB], sB = csum[rB] - cB2;
        int m = max(cA, cB2);
        #pragma unroll 2
        for (int j = 0; j < m; ++j) {
            if (j < cA) { int c = scol[sA + j]; GATHER(c, 0); }
            if (j < cB2) { int c = scol[sB + j]; GATHER(c, 8); }
        }
        __syncthreads();   // scol reused next chunk
    }
#undef GATHER

    // epilogue: out[r] = feat[r] + acc/max(deg,1); all lanes write
    {
        int r = cb * CB + rA;
        if (r < n_nodes) {
            float inv = 1.0f / fmaxf((float)ddeg[rA], 1.0f);
            size_t off = (size_t)r * D_FEAT + sub * 8;
            float4 f0 = *reinterpret_cast<const float4*>(feat + off);
            float4 f1 = *reinterpret_cast<const float4*>(feat + off + 4);
            float4 o0, o1;
            o0.x = f0.x + acc[0] * inv; o0.y = f0.y + acc[1] * inv;
            o0.z = f0.z + acc[2] * inv; o0.w = f0.w + acc[3] * inv;
            o1.x = f1.x + acc[4] * inv; o1.y = f1.y + acc[5] * inv;
            o1.z = f1.z + acc[6] * inv; o1.w = f1.w + acc[7] * inv;
            *reinterpret_cast<float4*>(out + off) = o0;
            *reinterpret_cast<float4*>(out + off + 4) = o1;
        }
        r = cb * CB + rB;
        if (r < n_nodes) {
            float inv = 1.0f / fmaxf((float)ddeg[rB], 1.0f);
            size_t off = (size_t)r * D_FEAT + sub * 8;
            float4 f0 = *reinterpret_cast<const float4*>(feat + off);
            float4 f1 = *reinterpret_cast<const float4*>(feat + off + 4);
            float4 o0, o1;
            o0.x = f0.x + acc[8]  * inv; o0.y = f0.y + acc[9]  * inv;
            o0.z = f0.z + acc[10] * inv; o0.w = f0.w + acc[11] * inv;
            o1.x = f1.x + acc[12] * inv; o1.y = f1.y + acc[13] * inv;
            o1.z = f1.z + acc[14] * inv; o1.w = f1.w + acc[15] * inv;
            *reinterpret_cast<float4*>(out + off) = o0;
            *reinterpret_cast<float4*>(out + off + 4) = o1;
        }
    }
}

extern "C" void kernel_launch(void* const* d_in, const int* in_sizes, int n_in,
                              void* d_out, int out_size, void* d_ws, size_t ws_size,
                              hipStream_t stream) {
    const float* feat = (const float*)d_in[0];
    const int* row = (const int*)d_in[1];
    const int* col = (const int*)d_in[2];
    float* out = (float*)d_out;

    const int n_nodes = in_sizes[0] / D_FEAT;
    const int n_edges = in_sizes[1];
    const int nb2 = (n_nodes + CB - 1) / CB;              // 391
    const int ebt = (n_edges + E_BLK - 1) / E_BLK;        // 196  (<= TMAX)
    const int n4 = n_nodes * D_FEAT / 4;                  // 1.6M float4s

    size_t tb_bytes  = (size_t)ebt * E_BLK * 4;           // 6.4 MB
    size_t cs_bytes  = (size_t)ebt * (nb2 + 1) * 4;       // 0.31 MB
    size_t bf_bytes  = (size_t)n_nodes * D_FEAT * 2;      // 12.8 MB

    size_t lean_need = tb_bytes + cs_bytes + 256;
    size_t fat_need  = lean_need + ((bf_bytes + 63) & ~(size_t)63);
    bool fat = (ws_size >= fat_need);

    char* ws = (char*)d_ws;
    size_t p = 0;
    int* tilebuf = (int*)(ws + p); p += tb_bytes;
    int* csumG   = (int*)(ws + p); p += cs_bytes;
    p = (p + 63) & ~(size_t)63;
    unsigned short* feat_bf = nullptr;
    if (fat) { feat_bf = (unsigned short*)(ws + p); }

    {
        int conv_blocks = fat ? (n4 + 1023) / 1024 : 0;
        bin5_conv_kernel<<<ebt + conv_blocks, 1024, 0, stream>>>(
            row, col, tilebuf, csumG, n_edges, ebt, nb2,
            feat, feat_bf, fat ? n4 : 0);
    }
    if (fat) {
        agg7_kernel<1><<<nb2, 1024, 0, stream>>>(
            feat, feat_bf, tilebuf, csumG, out, n_nodes, ebt, nb2);
    } else {
        agg7_kernel<0><<<nb2, 1024, 0, stream>>>(
            feat, nullptr, tilebuf, csumG, out, n_nodes, ebt, nb2);
    }
}